// Round 13
// baseline (41.630 us; speedup 1.0000x reference)
//
#include <hip/hip_runtime.h>
#include <hip/hip_bf16.h>
#include <math.h>

#define CCH   256      // IN_CHANNELS
#define HH    128
#define WW    128
#define EPSF  1e-12f
#define EPS81 8.1e-11f // 81 * 1e-12
#define SLOPE 0.2f

// pooled layout: [3][N][512]  (c -> mean part, 256+c -> std part)

__device__ __forceinline__ void k3_loadrow(const float* __restrict__ plane, int r, int jb,
                                           float4& rs, float4& rq) {
    const float* rp = &plane[r * WW + jb];
    float4 v = *reinterpret_cast<const float4*>(rp);       // cols jb..jb+3 (16B aligned)
    float2 w = *reinterpret_cast<const float2*>(rp + 4);   // cols jb+4, jb+5 (8B aligned)
    float t12 = v.y + v.z, t34 = v.w + w.x;
    rs.x = v.x + t12; rs.y = t12 + v.w; rs.z = v.z + t34; rs.w = t34 + w.y;
    float y0 = v.x * v.x, y1 = v.y * v.y, y2 = v.z * v.z;
    float y3 = v.w * v.w, y4 = w.x * w.x, y5 = w.y * w.y;
    float u12 = y1 + y2, u34 = y3 + y4;
    rq.x = y0 + u12; rq.y = u12 + y3; rq.z = y2 + u34; rq.w = u34 + y5;
}

__device__ __forceinline__ void win_acc(float S, float Q, float wm, float& aS, float& aD) {
    // std*9 = sqrt(max(9Q - S^2, 0) + 81*eps); accumulate masked
    float d = fmaxf(fmaf(S, -S, 9.f * Q), 0.f);
    aS = fmaf(wm, S, aS);
    aD = fmaf(wm, sqrtf(d + EPS81), aD);
}

__global__ __launch_bounds__(512, 4) void stats_kernel(const float* __restrict__ feat,
                                                       float* __restrict__ pooled,
                                                       int* __restrict__ bar,
                                                       int N) {
    __shared__ float plane[HH * WW + 8];      // 64 KB + pad
    __shared__ float wp[8][6];

    const int p    = blockIdx.x;              // n*C + c
    const int n    = p >> 8;
    const int c    = p & 255;
    const int tid  = threadIdx.x;
    const int wave = tid >> 6, lane = tid & 63;

    // Zero the MLP kernel's completion counter (race-free: stream order).
    if (p == 0 && tid < 8) bar[tid] = 0;

    // ---- stage plane into LDS via async global->LDS (16B/lane, linear layout) ----
    {
        const float* gbase = feat + (size_t)p * (HH * WW) + (tid << 2);
        #pragma unroll
        for (int i = 0; i < 8; ++i) {
            __builtin_amdgcn_global_load_lds(
                (const __attribute__((address_space(1))) void*)(gbase + i * 2048),
                (__attribute__((address_space(3))) void*)&plane[i * 2048 + (wave << 8)],
                16, 0, 0);
        }
        if (tid < 8) plane[HH * WW + tid] = 0.f;
    }
    __syncthreads();

    // =============== K = 3, stride 1, out 126x126 ===============
    float a3S = 0.f, a3D = 0.f;
    {
        const int s  = tid & 31;
        const int g  = tid >> 5;              // 0..15
        const int jb = s << 2;
        const float wm2 = (s < 31) ? 1.f : 0.f;
        const int i0 = g << 3;
        float4 r0s, r0q, r1s, r1q;
        k3_loadrow(plane, i0,     jb, r0s, r0q);
        k3_loadrow(plane, i0 + 1, jb, r1s, r1q);
        #pragma unroll
        for (int t = 0; t < 8; ++t) {
            const int i  = i0 + t;
            const int r2 = (i + 2 < 128) ? (i + 2) : 127;
            float4 r2s, r2q;
            k3_loadrow(plane, r2, jb, r2s, r2q);
            const float wr  = (i < 126) ? 1.f : 0.f;
            const float wrm = wr * wm2;
            float Sx = r0s.x + r1s.x + r2s.x, Qx = r0q.x + r1q.x + r2q.x;
            float Sy = r0s.y + r1s.y + r2s.y, Qy = r0q.y + r1q.y + r2q.y;
            float Sz = r0s.z + r1s.z + r2s.z, Qz = r0q.z + r1q.z + r2q.z;
            float Sw = r0s.w + r1s.w + r2s.w, Qw = r0q.w + r1q.w + r2q.w;
            win_acc(Sx, Qx, wr,  a3S, a3D);
            win_acc(Sy, Qy, wr,  a3S, a3D);
            win_acc(Sz, Qz, wrm, a3S, a3D);
            win_acc(Sw, Qw, wrm, a3S, a3D);
            r0s = r1s; r0q = r1q; r1s = r2s; r1q = r2q;
        }
    }

    // =============== K = 34, stride 16, out 6x6 ===============
    float am34 = 0.f, as34 = 0.f;
    for (int w = wave; w < 36; w += 8) {
        int wi = w / 6, wj = w - 6 * wi;
        int r0 = wi << 4, c0 = wj << 4;
        float S = 0.f, Q = 0.f;
        #pragma unroll
        for (int it = 0; it < 5; ++it) {
            int t = lane + (it << 6);
            if (t < 306) {                     // 34 rows x 9 float4-slots
                int r = t / 9, c4 = t - 9 * r;
                const float* rp = &plane[(r0 + r) * WW + c0 + (c4 << 2)];
                float4 v = *reinterpret_cast<const float4*>(rp);
                if (c4 == 8) { v.z = 0.f; v.w = 0.f; }
                S += (v.x + v.y) + (v.z + v.w);
                Q = fmaf(v.x, v.x, Q); Q = fmaf(v.y, v.y, Q);
                Q = fmaf(v.z, v.z, Q); Q = fmaf(v.w, v.w, Q);
            }
        }
        #pragma unroll
        for (int off = 32; off > 0; off >>= 1) {
            S += __shfl_down(S, off);
            Q += __shfl_down(Q, off);
        }
        if (lane == 0) {
            const float inv = 1.f / 1156.f;
            float mean = S * inv;
            float var  = fmaxf(fmaf(-mean, mean, Q * inv), 0.f);
            am34 += mean;
            as34 += sqrtf(var + EPSF);
        }
    }

    // =============== K = 65, stride 32, out 2x2 ===============
    float m65 = 0.f, s65 = 0.f;
    if (wave >= 4) {
        int w  = wave - 4;
        int wi = w >> 1, wj = w & 1;
        int r0 = wi << 5, c0 = wj << 5;
        float S = 0.f, Q = 0.f;
        #pragma unroll
        for (int it = 0; it < 18; ++it) {
            int t = lane + (it << 6);
            if (t < 1105) {                    // 65 rows x 17 float4-slots
                int r = t / 17, c4 = t - 17 * r;
                const float* rp = &plane[(r0 + r) * WW + c0 + (c4 << 2)];
                float4 v = *reinterpret_cast<const float4*>(rp);
                if (c4 == 16) { v.y = 0.f; v.z = 0.f; v.w = 0.f; }
                S += (v.x + v.y) + (v.z + v.w);
                Q = fmaf(v.x, v.x, Q); Q = fmaf(v.y, v.y, Q);
                Q = fmaf(v.z, v.z, Q); Q = fmaf(v.w, v.w, Q);
            }
        }
        #pragma unroll
        for (int off = 32; off > 0; off >>= 1) {
            S += __shfl_down(S, off);
            Q += __shfl_down(Q, off);
        }
        if (lane == 0) {
            const float inv = 1.f / 4225.f;
            float mean = S * inv;
            float var  = fmaxf(fmaf(-mean, mean, Q * inv), 0.f);
            m65 = mean;
            s65 = sqrtf(var + EPSF);
        }
    }

    // ---- reduce K3 partials across the wave, then one barrier + final reduce ----
    #pragma unroll
    for (int off = 32; off > 0; off >>= 1) {
        a3S += __shfl_down(a3S, off);
        a3D += __shfl_down(a3D, off);
    }
    if (lane == 0) {
        wp[wave][0] = a3S; wp[wave][1] = a3D;
        wp[wave][2] = am34; wp[wave][3] = as34;
        wp[wave][4] = m65;  wp[wave][5] = s65;
    }
    __syncthreads();
    if (tid == 0) {
        float A3 = 0.f, D3 = 0.f, M34 = 0.f, S34 = 0.f, M65 = 0.f, S65 = 0.f;
        #pragma unroll
        for (int w = 0; w < 8; ++w) {
            A3 += wp[w][0]; D3 += wp[w][1];
            M34 += wp[w][2]; S34 += wp[w][3];
            M65 += wp[w][4]; S65 += wp[w][5];
        }
        const float inv3 = 1.f / (9.f * 126.f * 126.f);
        pooled[(0 * N + n) * 512 + c]       = A3 * inv3;
        pooled[(0 * N + n) * 512 + 256 + c] = D3 * inv3;
        pooled[(1 * N + n) * 512 + c]       = M34 * (1.f / 36.f);
        pooled[(1 * N + n) * 512 + 256 + c] = S34 * (1.f / 36.f);
        pooled[(2 * N + n) * 512 + c]       = M65 * 0.25f;
        pooled[(2 * N + n) * 512 + 256 + c] = S65 * 0.25f;
    }
}

__device__ __forceinline__ float leaky(float v) { return v > 0.f ? v : SLOPE * v; }
__device__ __forceinline__ float dot4(float4 a, float4 b) {
    float s = a.x * b.x;
    s = fmaf(a.y, b.y, s);
    s = fmaf(a.z, b.z, s);
    s = fmaf(a.w, b.w, s);
    return s;
}

// Whole MLP for one (k, n) per block; 6 blocks x 1024 threads (16 waves).
// Row-parallel via 16-lane groups: each wave runs 4 rows concurrently ->
// 8 independent global loads in flight per iteration, and ONE 4-step
// shfl(width=16) tree reduces all 4 rows at once (1 DS-op/row).
// Inter-layer sync is block-local (__syncthreads). Last block sums losses.
__global__ __launch_bounds__(1024) void mlp_one(const float* __restrict__ pooled,
                                                const float* __restrict__ W1, const float* __restrict__ b1,
                                                const float* __restrict__ W2, const float* __restrict__ b2,
                                                const float* __restrict__ W3, const float* __restrict__ b3,
                                                const float* __restrict__ W4, const float* __restrict__ b4,
                                                const int* __restrict__ label,
                                                float* __restrict__ losses,
                                                int* __restrict__ bar,
                                                float* __restrict__ out) {
    __shared__ __align__(16) float h1s[256];
    __shared__ __align__(16) float h2s[256];
    __shared__ __align__(16) float h3s[128];
    __shared__ int winner;

    const int bk   = blockIdx.x;        // k*2 + n
    const int k    = bk >> 1;
    const int tid  = threadIdx.x;
    const int wave = tid >> 6, lane = tid & 63;
    const int lq   = lane & 15;         // lane within 16-lane group
    const int lg   = lane >> 4;         // group 0..3 -> row offset

    // x (512 floats): lane keeps float4s lq+16j, j=0..7  (32 floats/lane)
    const float4* x4 = reinterpret_cast<const float4*>(pooled + (size_t)bk * 512);
    float4 x0 = x4[lq], x1 = x4[lq + 16], x2 = x4[lq + 32], x3 = x4[lq + 48],
           x4v = x4[lq + 64], x5 = x4[lq + 80], x6 = x4[lq + 96], x7 = x4[lq + 112];

    // ---------------- L1: 512 -> 256 ----------------
    {
        const float4* W1b = reinterpret_cast<const float4*>(W1 + (size_t)k * 256 * 512);
        for (int it = 0; it < 4; ++it) {
            const int o = (wave << 4) + (it << 2) + lg;         // row 0..255
            const float4* wr = W1b + (size_t)o * 128 + lq;
            float4 w0 = wr[0],  w1 = wr[16], w2 = wr[32],  w3 = wr[48];
            float4 w4_ = wr[64], w5 = wr[80], w6 = wr[96], w7 = wr[112];
            float sA = dot4(w0, x0), sB = dot4(w1, x1);
            sA = fmaf(1.f, dot4(w2, x2), sA);  sB = fmaf(1.f, dot4(w3, x3), sB);
            sA += dot4(w4_, x4v);              sB += dot4(w5, x5);
            sA += dot4(w6, x6);                sB += dot4(w7, x7);
            float s = sA + sB;
            s += __shfl_down(s, 8, 16);
            s += __shfl_down(s, 4, 16);
            s += __shfl_down(s, 2, 16);
            s += __shfl_down(s, 1, 16);
            if (lq == 0) h1s[o] = leaky(s + b1[(size_t)k * 256 + o]);
        }
    }
    __syncthreads();

    // ---------------- L2: 256 -> 256 ----------------
    {
        const float4* h14 = reinterpret_cast<const float4*>(h1s);
        float4 a0 = h14[lq], a1 = h14[lq + 16], a2 = h14[lq + 32], a3 = h14[lq + 48];
        const float4* W2b = reinterpret_cast<const float4*>(W2 + (size_t)k * 256 * 256);
        for (int it = 0; it < 4; ++it) {
            const int o = (wave << 4) + (it << 2) + lg;
            const float4* wr = W2b + (size_t)o * 64 + lq;
            float4 w0 = wr[0], w1 = wr[16], w2 = wr[32], w3 = wr[48];
            float s = dot4(w0, a0) + dot4(w1, a1) + dot4(w2, a2) + dot4(w3, a3);
            s += __shfl_down(s, 8, 16);
            s += __shfl_down(s, 4, 16);
            s += __shfl_down(s, 2, 16);
            s += __shfl_down(s, 1, 16);
            if (lq == 0) h2s[o] = leaky(s + b2[(size_t)k * 256 + o]);
        }
    }
    __syncthreads();

    // ---------------- L3: 256 -> 128 ----------------
    {
        const float4* h24 = reinterpret_cast<const float4*>(h2s);
        float4 a0 = h24[lq], a1 = h24[lq + 16], a2 = h24[lq + 32], a3 = h24[lq + 48];
        const float4* W3b = reinterpret_cast<const float4*>(W3 + (size_t)k * 128 * 256);
        for (int it = 0; it < 2; ++it) {
            const int o = (wave << 3) + (it << 2) + lg;         // row 0..127
            const float4* wr = W3b + (size_t)o * 64 + lq;
            float4 w0 = wr[0], w1 = wr[16], w2 = wr[32], w3 = wr[48];
            float s = dot4(w0, a0) + dot4(w1, a1) + dot4(w2, a2) + dot4(w3, a3);
            s += __shfl_down(s, 8, 16);
            s += __shfl_down(s, 4, 16);
            s += __shfl_down(s, 2, 16);
            s += __shfl_down(s, 1, 16);
            if (lq == 0) h3s[o] = leaky(s + b3[(size_t)k * 128 + o]);
        }
    }
    __syncthreads();

    // ---------------- L4: 128 -> 1 + loss ----------------
    if (wave == 0) {
        float s = 0.f;
        if (lane < 32) {
            float4 wv = reinterpret_cast<const float4*>(W4 + (size_t)k * 128)[lane];
            float4 hv = reinterpret_cast<const float4*>(h3s)[lane];
            s = dot4(wv, hv);
        }
        #pragma unroll
        for (int off = 16; off > 0; off >>= 1) s += __shfl_down(s, off);
        s += __shfl_down(s, 16);   // no-op safety not needed; kept ordering simple
        if (lane == 0) {
            // redo clean 32-lane reduction result: s currently lane0 sum of 0..31
            float logit = s + b4[k];
            float y = (float)(*label);
            float sp = fmaxf(logit, 0.f) + log1pf(expf(-fabsf(logit)));
            losses[bk] = sp - logit * y;
        }
    }

    // ---------------- last-block tail: deterministic total ----------------
    __syncthreads();
    if (tid == 0) {
        __threadfence();   // release losses[bk]
        int prev = __hip_atomic_fetch_add(&bar[0], 1, __ATOMIC_ACQ_REL,
                                          __HIP_MEMORY_SCOPE_AGENT);
        winner = (prev == 5) ? 1 : 0;
    }
    __syncthreads();
    if (winner && tid == 0) {
        __threadfence();   // acquire all losses
        float tot = 0.f;
        #pragma unroll
        for (int kk = 0; kk < 3; ++kk)
            tot += (losses[kk * 2 + 0] + losses[kk * 2 + 1]) * 0.5f;
        out[0] = tot;
    }
}

extern "C" void kernel_launch(void* const* d_in, const int* in_sizes, int n_in,
                              void* d_out, int out_size, void* d_ws, size_t ws_size,
                              hipStream_t stream) {
    const float* feat = (const float*)d_in[0];
    const float* W1   = (const float*)d_in[1];
    const float* b1   = (const float*)d_in[2];
    const float* W2   = (const float*)d_in[3];
    const float* b2   = (const float*)d_in[4];
    const float* W3   = (const float*)d_in[5];
    const float* b3   = (const float*)d_in[6];
    const float* W4   = (const float*)d_in[7];
    const float* b4   = (const float*)d_in[8];
    const int* label  = (const int*)d_in[9];

    const int N = in_sizes[0] / (CCH * HH * WW);   // = 2

    float* pooled = (float*)d_ws;                     // [3][N][512]
    float* losses = pooled + (size_t)3 * N * 512;     // [6]
    int*   bar    = (int*)(losses + 8);               // 8 ints (zeroed by stats node)

    stats_kernel<<<N * CCH, 512, 0, stream>>>(feat, pooled, bar, N);

    mlp_one<<<3 * N, 1024, 0, stream>>>(pooled, W1, b1, W2, b2, W3, b3, W4, b4,
                                        label, losses, bar, (float*)d_out);
}

// Round 14
// 36.068 us; speedup vs baseline: 1.1542x; 1.1542x over previous
//
#include <hip/hip_runtime.h>
#include <hip/hip_bf16.h>
#include <math.h>

#define CCH   256      // IN_CHANNELS
#define HH    128
#define WW    128
#define EPSF  1e-12f
#define EPS81 8.1e-11f // 81 * 1e-12
#define SLOPE 0.2f

// pooled layout: [3][N][512]  (c -> mean part, 256+c -> std part)

__device__ __forceinline__ void k3_loadrow(const float* __restrict__ plane, int r, int jb,
                                           float4& rs, float4& rq) {
    const float* rp = &plane[r * WW + jb];
    float4 v = *reinterpret_cast<const float4*>(rp);       // cols jb..jb+3 (16B aligned)
    float2 w = *reinterpret_cast<const float2*>(rp + 4);   // cols jb+4, jb+5 (8B aligned)
    float t12 = v.y + v.z, t34 = v.w + w.x;
    rs.x = v.x + t12; rs.y = t12 + v.w; rs.z = v.z + t34; rs.w = t34 + w.y;
    float y0 = v.x * v.x, y1 = v.y * v.y, y2 = v.z * v.z;
    float y3 = v.w * v.w, y4 = w.x * w.x, y5 = w.y * w.y;
    float u12 = y1 + y2, u34 = y3 + y4;
    rq.x = y0 + u12; rq.y = u12 + y3; rq.z = y2 + u34; rq.w = u34 + y5;
}

__device__ __forceinline__ void win_acc(float S, float Q, float wm, float& aS, float& aD) {
    // std*9 = sqrt(max(9Q - S^2, 0) + 81*eps); accumulate masked
    float d = fmaxf(fmaf(S, -S, 9.f * Q), 0.f);
    aS = fmaf(wm, S, aS);
    aD = fmaf(wm, sqrtf(d + EPS81), aD);
}

__device__ __forceinline__ void keep_alive(float4 v) {
    asm volatile("" :: "v"(v.x), "v"(v.y), "v"(v.z), "v"(v.w));
}

__global__ __launch_bounds__(512, 4) void stats_kernel(const float* __restrict__ feat,
                                                       float* __restrict__ pooled,
                                                       const float* __restrict__ W1,
                                                       const float* __restrict__ W2,
                                                       const float* __restrict__ W3,
                                                       const float* __restrict__ W4,
                                                       int N) {
    __shared__ float plane[HH * WW + 8];      // 64 KB + pad
    __shared__ float wp[8][6];

    const int p    = blockIdx.x;              // n*C + c
    const int n    = p >> 8;
    const int c    = p & 255;
    const int tid  = threadIdx.x;
    const int wave = tid >> 6, lane = tid & 63;

    // ---- stage plane into LDS via async global->LDS (16B/lane, linear layout) ----
    {
        const float* gbase = feat + (size_t)p * (HH * WW) + (tid << 2);
        #pragma unroll
        for (int i = 0; i < 8; ++i) {
            __builtin_amdgcn_global_load_lds(
                (const __attribute__((address_space(1))) void*)(gbase + i * 2048),
                (__attribute__((address_space(3))) void*)&plane[i * 2048 + (wave << 8)],
                16, 0, 0);
        }
        if (tid < 8) plane[HH * WW + tid] = 0.f;
    }

    // ---- weight prefetch into L2/L3, hidden under stats compute ----
    // W1: 98304 f4 -> 192/block; W2: 49152 -> 96/block; W3: 24576 -> 48/block;
    // W4: 96 f4 on block 0. Loads kept alive via empty asm (no DCE), results unused.
    {
        const float4* w1f4 = reinterpret_cast<const float4*>(W1);
        const float4* w2f4 = reinterpret_cast<const float4*>(W2);
        const float4* w3f4 = reinterpret_cast<const float4*>(W3);
        if (tid < 192) keep_alive(w1f4[(size_t)p * 192 + tid]);
        if (tid < 96)  keep_alive(w2f4[(size_t)p * 96 + tid]);
        if (tid < 48)  keep_alive(w3f4[(size_t)p * 48 + tid]);
        if (p == 0 && tid < 96)
            keep_alive(reinterpret_cast<const float4*>(W4)[tid]);
    }
    __syncthreads();

    // =============== K = 3, stride 1, out 126x126 ===============
    float a3S = 0.f, a3D = 0.f;
    {
        const int s  = tid & 31;
        const int g  = tid >> 5;              // 0..15
        const int jb = s << 2;
        const float wm2 = (s < 31) ? 1.f : 0.f;
        const int i0 = g << 3;
        float4 r0s, r0q, r1s, r1q;
        k3_loadrow(plane, i0,     jb, r0s, r0q);
        k3_loadrow(plane, i0 + 1, jb, r1s, r1q);
        #pragma unroll
        for (int t = 0; t < 8; ++t) {
            const int i  = i0 + t;
            const int r2 = (i + 2 < 128) ? (i + 2) : 127;
            float4 r2s, r2q;
            k3_loadrow(plane, r2, jb, r2s, r2q);
            const float wr  = (i < 126) ? 1.f : 0.f;
            const float wrm = wr * wm2;
            float Sx = r0s.x + r1s.x + r2s.x, Qx = r0q.x + r1q.x + r2q.x;
            float Sy = r0s.y + r1s.y + r2s.y, Qy = r0q.y + r1q.y + r2q.y;
            float Sz = r0s.z + r1s.z + r2s.z, Qz = r0q.z + r1q.z + r2q.z;
            float Sw = r0s.w + r1s.w + r2s.w, Qw = r0q.w + r1q.w + r2q.w;
            win_acc(Sx, Qx, wr,  a3S, a3D);
            win_acc(Sy, Qy, wr,  a3S, a3D);
            win_acc(Sz, Qz, wrm, a3S, a3D);
            win_acc(Sw, Qw, wrm, a3S, a3D);
            r0s = r1s; r0q = r1q; r1s = r2s; r1q = r2q;
        }
    }

    // =============== K = 34, stride 16, out 6x6 ===============
    float am34 = 0.f, as34 = 0.f;
    for (int w = wave; w < 36; w += 8) {
        int wi = w / 6, wj = w - 6 * wi;
        int r0 = wi << 4, c0 = wj << 4;
        float S = 0.f, Q = 0.f;
        #pragma unroll
        for (int it = 0; it < 5; ++it) {
            int t = lane + (it << 6);
            if (t < 306) {                     // 34 rows x 9 float4-slots
                int r = t / 9, c4 = t - 9 * r;
                const float* rp = &plane[(r0 + r) * WW + c0 + (c4 << 2)];
                float4 v = *reinterpret_cast<const float4*>(rp);
                if (c4 == 8) { v.z = 0.f; v.w = 0.f; }
                S += (v.x + v.y) + (v.z + v.w);
                Q = fmaf(v.x, v.x, Q); Q = fmaf(v.y, v.y, Q);
                Q = fmaf(v.z, v.z, Q); Q = fmaf(v.w, v.w, Q);
            }
        }
        #pragma unroll
        for (int off = 32; off > 0; off >>= 1) {
            S += __shfl_down(S, off);
            Q += __shfl_down(Q, off);
        }
        if (lane == 0) {
            const float inv = 1.f / 1156.f;
            float mean = S * inv;
            float var  = fmaxf(fmaf(-mean, mean, Q * inv), 0.f);
            am34 += mean;
            as34 += sqrtf(var + EPSF);
        }
    }

    // =============== K = 65, stride 32, out 2x2 ===============
    float m65 = 0.f, s65 = 0.f;
    if (wave >= 4) {
        int w  = wave - 4;
        int wi = w >> 1, wj = w & 1;
        int r0 = wi << 5, c0 = wj << 5;
        float S = 0.f, Q = 0.f;
        #pragma unroll
        for (int it = 0; it < 18; ++it) {
            int t = lane + (it << 6);
            if (t < 1105) {                    // 65 rows x 17 float4-slots
                int r = t / 17, c4 = t - 17 * r;
                const float* rp = &plane[(r0 + r) * WW + c0 + (c4 << 2)];
                float4 v = *reinterpret_cast<const float4*>(rp);
                if (c4 == 16) { v.y = 0.f; v.z = 0.f; v.w = 0.f; }
                S += (v.x + v.y) + (v.z + v.w);
                Q = fmaf(v.x, v.x, Q); Q = fmaf(v.y, v.y, Q);
                Q = fmaf(v.z, v.z, Q); Q = fmaf(v.w, v.w, Q);
            }
        }
        #pragma unroll
        for (int off = 32; off > 0; off >>= 1) {
            S += __shfl_down(S, off);
            Q += __shfl_down(Q, off);
        }
        if (lane == 0) {
            const float inv = 1.f / 4225.f;
            float mean = S * inv;
            float var  = fmaxf(fmaf(-mean, mean, Q * inv), 0.f);
            m65 = mean;
            s65 = sqrtf(var + EPSF);
        }
    }

    // ---- reduce K3 partials across the wave, then one barrier + final reduce ----
    #pragma unroll
    for (int off = 32; off > 0; off >>= 1) {
        a3S += __shfl_down(a3S, off);
        a3D += __shfl_down(a3D, off);
    }
    if (lane == 0) {
        wp[wave][0] = a3S; wp[wave][1] = a3D;
        wp[wave][2] = am34; wp[wave][3] = as34;
        wp[wave][4] = m65;  wp[wave][5] = s65;
    }
    __syncthreads();
    if (tid == 0) {
        float A3 = 0.f, D3 = 0.f, M34 = 0.f, S34 = 0.f, M65 = 0.f, S65 = 0.f;
        #pragma unroll
        for (int w = 0; w < 8; ++w) {
            A3 += wp[w][0]; D3 += wp[w][1];
            M34 += wp[w][2]; S34 += wp[w][3];
            M65 += wp[w][4]; S65 += wp[w][5];
        }
        const float inv3 = 1.f / (9.f * 126.f * 126.f);
        pooled[(0 * N + n) * 512 + c]       = A3 * inv3;
        pooled[(0 * N + n) * 512 + 256 + c] = D3 * inv3;
        pooled[(1 * N + n) * 512 + c]       = M34 * (1.f / 36.f);
        pooled[(1 * N + n) * 512 + 256 + c] = S34 * (1.f / 36.f);
        pooled[(2 * N + n) * 512 + c]       = M65 * 0.25f;
        pooled[(2 * N + n) * 512 + 256 + c] = S65 * 0.25f;
    }
}

__device__ __forceinline__ float leaky(float v) { return v > 0.f ? v : SLOPE * v; }

// One wave per output row (k, o); float4 loads; both n samples per weight read.
__global__ __launch_bounds__(256) void layer_kernel(const float* __restrict__ W,
                                                    const float* __restrict__ b,
                                                    const float* __restrict__ xin,
                                                    float* __restrict__ xout,
                                                    int DIN, int DOUT, int act) {
    const int wave = threadIdx.x >> 6, lane = threadIdx.x & 63;
    const int r = blockIdx.x * 4 + wave;           // row over 3*DOUT
    if (r >= 3 * DOUT) return;
    const int k = r / DOUT, o = r - k * DOUT;
    const int DIN4 = DIN >> 2;

    const float4* w4  = reinterpret_cast<const float4*>(W + ((size_t)k * DOUT + o) * DIN);
    const float4* x04 = reinterpret_cast<const float4*>(xin + (size_t)(k * 2 + 0) * DIN);
    const float4* x14 = reinterpret_cast<const float4*>(xin + (size_t)(k * 2 + 1) * DIN);

    float s0 = 0.f, s1 = 0.f;
    for (int j = lane; j < DIN4; j += 64) {
        float4 wv = w4[j], a = x04[j], d = x14[j];
        s0 = fmaf(wv.x, a.x, s0); s0 = fmaf(wv.y, a.y, s0);
        s0 = fmaf(wv.z, a.z, s0); s0 = fmaf(wv.w, a.w, s0);
        s1 = fmaf(wv.x, d.x, s1); s1 = fmaf(wv.y, d.y, s1);
        s1 = fmaf(wv.z, d.z, s1); s1 = fmaf(wv.w, d.w, s1);
    }
    #pragma unroll
    for (int off = 32; off > 0; off >>= 1) {
        s0 += __shfl_down(s0, off);
        s1 += __shfl_down(s1, off);
    }
    if (lane == 0) {
        float bb = b[k * DOUT + o];
        float v0 = s0 + bb, v1 = s1 + bb;
        if (act) { v0 = leaky(v0); v1 = leaky(v1); }
        xout[(size_t)(k * 2 + 0) * DOUT + o] = v0;
        xout[(size_t)(k * 2 + 1) * DOUT + o] = v1;
    }
}

// Final layer 128->1 + softplus loss + deterministic total. One block, 384 threads.
__global__ __launch_bounds__(384) void final_kernel(const float* __restrict__ W4,
                                                    const float* __restrict__ b4,
                                                    const float* __restrict__ h3,
                                                    const int* __restrict__ label,
                                                    float* __restrict__ out) {
    __shared__ float lossArr[6];
    const int wave = threadIdx.x >> 6, lane = threadIdx.x & 63;
    {
        const int k = wave >> 1, n = wave & 1;
        const float* w = &W4[(size_t)k * 128];
        const float* x = &h3[(size_t)(k * 2 + n) * 128];
        float s = w[lane] * x[lane] + w[lane + 64] * x[lane + 64];
        #pragma unroll
        for (int off = 32; off > 0; off >>= 1) s += __shfl_down(s, off);
        if (lane == 0) {
            float logit = s + b4[k];
            float y = (float)(*label);
            float sp = fmaxf(logit, 0.f) + log1pf(expf(-fabsf(logit)));
            lossArr[wave] = sp - logit * y;
        }
    }
    __syncthreads();
    if (threadIdx.x == 0) {
        float tot = 0.f;
        #pragma unroll
        for (int k = 0; k < 3; ++k)
            tot += (lossArr[k * 2 + 0] + lossArr[k * 2 + 1]) * 0.5f;
        out[0] = tot;
    }
}

extern "C" void kernel_launch(void* const* d_in, const int* in_sizes, int n_in,
                              void* d_out, int out_size, void* d_ws, size_t ws_size,
                              hipStream_t stream) {
    const float* feat = (const float*)d_in[0];
    const float* W1   = (const float*)d_in[1];
    const float* b1   = (const float*)d_in[2];
    const float* W2   = (const float*)d_in[3];
    const float* b2   = (const float*)d_in[4];
    const float* W3   = (const float*)d_in[5];
    const float* b3   = (const float*)d_in[6];
    const float* W4   = (const float*)d_in[7];
    const float* b4   = (const float*)d_in[8];
    const int* label  = (const int*)d_in[9];

    const int N = in_sizes[0] / (CCH * HH * WW);   // = 2

    float* pooled = (float*)d_ws;                   // [3][N][512]
    float* h1     = pooled + (size_t)3 * N * 512;   // [3][N][256]
    float* h2     = h1     + (size_t)3 * N * 256;   // [3][N][256]
    float* h3     = h2     + (size_t)3 * N * 256;   // [3][N][128]

    stats_kernel<<<N * CCH, 512, 0, stream>>>(feat, pooled, W1, W2, W3, W4, N);

    layer_kernel<<<192, 256, 0, stream>>>(W1, b1, pooled, h1, 512, 256, 1);
    layer_kernel<<<192, 256, 0, stream>>>(W2, b2, h1, h2, 256, 256, 1);
    layer_kernel<<<96, 256, 0, stream>>>(W3, b3, h2, h3, 256, 128, 1);
    final_kernel<<<1, 384, 0, stream>>>(W4, b4, h3, label, (float*)d_out);
}